// Round 10
// baseline (5872.119 us; speedup 1.0000x reference)
//
#include <hip/hip_runtime.h>
#include <stdint.h>

#define NTOK  32000
#define NINP  512
#define NHID  1024
#define NBATCH 64
#define NTIME 512
#define NGATE 4096
#define H3    341   // NHID/3

typedef __attribute__((ext_vector_type(8))) short  short8;
typedef __attribute__((ext_vector_type(4))) float  floatx4;
typedef unsigned long long ull;

#define HBUF_DW (NBATCH * NHID / 2)  // 32768 dwords per h buffer

__device__ __forceinline__ unsigned short f2bf(float f) {
  union { float f; unsigned u; } v; v.f = f;
  unsigned r = v.u + 0x7fffu + ((v.u >> 16) & 1u);
  return (unsigned short)(r >> 16);
}
__device__ __forceinline__ float bf2f(unsigned short h) {
  union { unsigned u; float f; } v; v.u = ((unsigned)h) << 16;
  return v.f;
}

// packed col p -> original gate row g = q*NHID + u
// p = cb*128 + w*32 + uu*4 + q ; u = cb*32 + w*8 + uu
__device__ __forceinline__ int pack2gate(int p) {
  int cb = p >> 7, r7 = p & 127;
  int w = r7 >> 5, r5 = r7 & 31;
  int uu = r5 >> 2, q = r5 & 3;
  int u = cb * 32 + w * 8 + uu;
  return q * NHID + u;
}

// ---------------- prep kernels ----------------

__global__ void k_pack_w(const float* __restrict__ src, unsigned short* __restrict__ dst, int K) {
  int p = blockIdx.x;
  int g = pack2gate(p);
  const float* s = src + (size_t)g * K;
  unsigned short* d = dst + (size_t)p * K;
  for (int k = threadIdx.x * 2; k < K; k += 512) {
    d[k] = f2bf(s[k]);
    d[k + 1] = f2bf(s[k + 1]);
  }
}

__global__ void k_bias(const float* __restrict__ bih, const float* __restrict__ bhh,
                       float* __restrict__ bp) {
  int p = blockIdx.x * 256 + threadIdx.x;
  if (p < NGATE) { int g = pack2gate(p); bp[p] = bih[g] + bhh[g]; }
}

__global__ void k_hbuf(const float* __restrict__ hx, unsigned short* __restrict__ hbuf) {
  int i = blockIdx.x * 256 + threadIdx.x;
  if (i < NBATCH * NHID) hbuf[i] = f2bf(hx[i]);
}

// gather embeddings for one chunk: Ag[row][k] bf16, row = tl*64 + b
__global__ void k_gather(const int* __restrict__ input, const float* __restrict__ emb,
                         unsigned short* __restrict__ Ag, int t0, int Tc) {
  int total = Tc * 64 * (NINP / 8);
  for (int ci = blockIdx.x * 256 + threadIdx.x; ci < total; ci += gridDim.x * 256) {
    int row = ci >> 6;
    int k8 = (ci & 63) * 8;
    int b = row & 63;
    int tl = row >> 6;
    int tok = input[(size_t)b * NTIME + t0 + tl];
    const float* s = emb + (size_t)tok * NINP + k8;
    unsigned short* d = Ag + (size_t)row * NINP + k8;
#pragma unroll
    for (int j = 0; j < 8; ++j) d[j] = f2bf(s[j]);
  }
}

// ---------------- x_proj GEMM -> FRAGMENT-ORDERED xproj ----------------
// xprojF element index: ((((tl*8+rg)*32+cb)*4+w)*32 + l)*8 + j*2 + s
// holds gate(row = rg*8 + (l>>4)*4 + j, col = cb*128 + w*32 + s*16 + (l&15))

__global__ __launch_bounds__(256) void k_gemm(const unsigned short* __restrict__ Ag,
                                              const unsigned short* __restrict__ Wp,
                                              const float* __restrict__ biasP,
                                              unsigned short* __restrict__ xprojF, int M) {
  __shared__ __attribute__((aligned(16))) unsigned short As[128 * 64];
  __shared__ __attribute__((aligned(16))) unsigned short Bs[128 * 64];
  const int tid = threadIdx.x;
  const int lane = tid & 63;
  const int w = tid >> 6;
  const int wr = w >> 1, wc = w & 1;
  const size_t rowbase = (size_t)blockIdx.x * 128;
  const int pbase = blockIdx.y * 128;

  floatx4 z = {0.f, 0.f, 0.f, 0.f};
  floatx4 acc[4][4];
#pragma unroll
  for (int i = 0; i < 4; ++i)
#pragma unroll
    for (int j = 0; j < 4; ++j) acc[i][j] = z;

  for (int kk = 0; kk < NINP; kk += 64) {
#pragma unroll
    for (int j = 0; j < 4; ++j) {
      int ci = j * 256 + tid;
      int r = ci >> 3;
      int kb = (ci & 7) * 16;
      int dst = r * 128 + (kb ^ ((r & 7) << 4));
      *(short8*)((char*)As + dst) =
          *(const short8*)((const char*)Ag + ((rowbase + r) * NINP + kk) * 2 + kb);
      *(short8*)((char*)Bs + dst) =
          *(const short8*)((const char*)Wp + ((size_t)(pbase + r) * NINP + kk) * 2 + kb);
    }
    __syncthreads();
#pragma unroll
    for (int k32 = 0; k32 < 2; ++k32) {
      short8 af[4], bfr[4];
      int kq = k32 * 64 + (lane >> 4) * 16;
#pragma unroll
      for (int t = 0; t < 4; ++t) {
        int r = wr * 64 + t * 16 + (lane & 15);
        af[t] = *(const short8*)((const char*)As + r * 128 + (kq ^ ((r & 7) << 4)));
        int cc = wc * 64 + t * 16 + (lane & 15);
        bfr[t] = *(const short8*)((const char*)Bs + cc * 128 + (kq ^ ((cc & 7) << 4)));
      }
#pragma unroll
      for (int tm = 0; tm < 4; ++tm)
#pragma unroll
        for (int tn = 0; tn < 4; ++tn)
          acc[tm][tn] = __builtin_amdgcn_mfma_f32_16x16x32_bf16(af[tm], bfr[tn], acc[tm][tn], 0, 0, 0);
    }
    __syncthreads();
  }
  // epilogue: scatter into fragment-ordered layout (2B stores, same count as before)
#pragma unroll
  for (int tn = 0; tn < 4; ++tn) {
    int p = pbase + wc * 64 + tn * 16 + (lane & 15);
    float bv = biasP[p];
    int cb2 = p >> 7, w2 = (p >> 5) & 3, c5 = p & 31;
    int s = c5 >> 4, c0b = c5 & 15;
#pragma unroll
    for (int tm = 0; tm < 4; ++tm) {
      size_t r0 = rowbase + wr * 64 + tm * 16 + ((lane >> 4) * 4);
#pragma unroll
      for (int j = 0; j < 4; ++j) {
        size_t r = r0 + j;
        int tl2 = (int)(r >> 6), b = (int)(r & 63);
        int rg2 = b >> 3, ur = b & 7;
        int l2 = ((ur >> 2) << 4) | c0b;
        size_t idx = ((((size_t)(tl2 * 8 + rg2) * 32 + cb2) * 4 + w2) * 32 + l2) * 8 +
                     (size_t)(ur & 3) * 2 + s;
        xprojF[idx] = f2bf(acc[tm][tn][j] + bv);
      }
    }
  }
}

// ---------------- persistent LSTM recurrence ----------------
// 256 blocks x 256 thr: rg = bid&7 (8 batch rows), cb = bid>>3 (128 packed cols).
// Weights register-resident. ONE __syncthreads per step (after hs staging);
// hs double-buffered by step parity; x fragments in registers (no xs LDS);
// per-WAVE flags posted right after per-wave vmcnt(0) drain; all lanes poll.

__global__ __launch_bounds__(256, 1) void k_rec(const unsigned short* __restrict__ Whp,
                                                const unsigned short* __restrict__ xprojF,
                                                unsigned* __restrict__ hbuf,
                                                float* __restrict__ cbuf,
                                                float* __restrict__ featbuf,
                                                const float* __restrict__ cx_in,
                                                const int* __restrict__ seq_len,
                                                float* __restrict__ out,
                                                unsigned* __restrict__ flags, int t0, int Tc) {
  __shared__ __attribute__((aligned(16))) unsigned short hs[2][8 * NHID];  // 2x16KB swizzled
  __shared__ __attribute__((aligned(16))) float gs[4][32][8];              // 4KB

  const int tid = threadIdx.x;
  const int lane = tid & 63;
  const int w = tid >> 6;
  const int rg = blockIdx.x & 7;
  const int cb = blockIdx.x >> 3;
  const int colbase = cb * 128 + w * 32;

  // persistent weight fragments: wave covers 32 packed cols, full K=1024
  short8 wf[64];
  {
    const int c0 = lane & 15;
    const int ke = (lane >> 4) * 8;
#pragma unroll
    for (int i = 0; i < 64; ++i) {
      int kk = i >> 1, n = i & 1;
      wf[i] = *(const short8*)(Whp + (size_t)(colbase + n * 16 + c0) * NHID + kk * 32 + ke);
    }
  }

  const int urow = lane >> 3;  // 0..7
  const int uu = lane & 7;     // 0..7
  const int row_g = rg * 8 + urow;
  const int u_g = cb * 32 + w * 8 + uu;
  float c = (t0 == 0) ? cx_in[row_g * NHID + u_g] : cbuf[row_g * NHID + u_g];
  float feat = (t0 == 0) ? 0.f : featbuf[row_g * NHID + u_g];
  const int sl = seq_len[row_g];

  // x fragment prefetch (one 16B load per lane<32 per step)
  const char* xB = (const char*)xprojF;
  short8 xr = {0, 0, 0, 0, 0, 0, 0, 0};
  if (lane < 32)
    xr = *(const short8*)(xB + ((((size_t)0 * 8 + rg) * 32 + cb) * 4 + w) * 512 + (size_t)lane * 16);

  for (int tl = 0; tl < Tc; ++tl) {
    const int tglob = t0 + tl;
    const int buf = tglob & 1;
    // dword-unit arithmetic on unsigned* base, THEN cast (R5 lesson)
    const short8* hp =
        (const short8*)(hbuf + (size_t)buf * HBUF_DW + (size_t)rg * 8 * (NHID / 2));
    unsigned short* hsb = hs[buf];

    // stage h (8 rows x 1024 bf16, 16KB): 4x16B agent(sc1) loads per thread
    {
      short8 q0, q1, q2, q3;
      asm volatile(
          "global_load_dwordx4 %0, %4, off sc1\n\t"
          "global_load_dwordx4 %1, %5, off sc1\n\t"
          "global_load_dwordx4 %2, %6, off sc1\n\t"
          "global_load_dwordx4 %3, %7, off sc1\n\t"
          "s_waitcnt vmcnt(0)"
          : "=&v"(q0), "=&v"(q1), "=&v"(q2), "=&v"(q3)
          : "v"(hp + tid), "v"(hp + 256 + tid), "v"(hp + 512 + tid), "v"(hp + 768 + tid)
          : "memory");
      int ci, r, kb;
      ci = tid;       r = ci >> 7; kb = (ci & 127) * 16;
      *(short8*)((char*)hsb + r * 2048 + (kb ^ ((r & 7) << 4))) = q0;
      ci = 256 + tid; r = ci >> 7; kb = (ci & 127) * 16;
      *(short8*)((char*)hsb + r * 2048 + (kb ^ ((r & 7) << 4))) = q1;
      ci = 512 + tid; r = ci >> 7; kb = (ci & 127) * 16;
      *(short8*)((char*)hsb + r * 2048 + (kb ^ ((r & 7) << 4))) = q2;
      ci = 768 + tid; r = ci >> 7; kb = (ci & 127) * 16;
      *(short8*)((char*)hsb + r * 2048 + (kb ^ ((r & 7) << 4))) = q3;
    }
    __syncthreads();  // the ONLY barrier per step: hs[buf] fully staged

    // prefetch next step's x fragment (hides under MFMA)
    short8 xr2 = {0, 0, 0, 0, 0, 0, 0, 0};
    if (lane < 32 && tl + 1 < Tc)
      xr2 = *(const short8*)(xB + ((((size_t)(tl + 1) * 8 + rg) * 32 + cb) * 4 + w) * 512 +
                             (size_t)lane * 16);

    // gates = h @ Whp^T, fp32 accum, 4 chains, ds_reads pipelined 1 pair ahead
    floatx4 acc0a = {0.f, 0.f, 0.f, 0.f}, acc0b = {0.f, 0.f, 0.f, 0.f};
    floatx4 acc1a = {0.f, 0.f, 0.f, 0.f}, acc1b = {0.f, 0.f, 0.f, 0.f};
    {
      const int rrc = lane & 7;  // A rows 8-15 duplicate 0-7; D rows 8-15 discarded
      const int kq = (lane >> 4) * 16;
      const char* hrow = (const char*)hsb + rrc * 2048;
      const int sw = rrc << 4;
      short8 aA = *(const short8*)(hrow + ((0 * 64 + kq) ^ sw));
      short8 aB = *(const short8*)(hrow + ((1 * 64 + kq) ^ sw));
#pragma unroll
      for (int kk = 0; kk < 32; kk += 2) {
        short8 nA = aA, nB = aB;
        if (kk < 30) {
          nA = *(const short8*)(hrow + (((kk + 2) * 64 + kq) ^ sw));
          nB = *(const short8*)(hrow + (((kk + 3) * 64 + kq) ^ sw));
        }
        acc0a = __builtin_amdgcn_mfma_f32_16x16x32_bf16(aA, wf[2 * kk + 0], acc0a, 0, 0, 0);
        acc1a = __builtin_amdgcn_mfma_f32_16x16x32_bf16(aA, wf[2 * kk + 1], acc1a, 0, 0, 0);
        acc0b = __builtin_amdgcn_mfma_f32_16x16x32_bf16(aB, wf[2 * kk + 2], acc0b, 0, 0, 0);
        acc1b = __builtin_amdgcn_mfma_f32_16x16x32_bf16(aB, wf[2 * kk + 3], acc1b, 0, 0, 0);
        aA = nA; aB = nB;
      }
    }
    floatx4 acc0 = acc0a + acc0b;
    floatx4 acc1 = acc1a + acc1b;

    // add x fragment (registers), dump gates to per-wave LDS
    if (lane < 32) {
      int r0 = (lane >> 4) * 4;
      int c0 = lane & 15;
      floatx4 g0, g1;
#pragma unroll
      for (int j = 0; j < 4; ++j) {
        g0[j] = acc0[j] + bf2f((unsigned short)xr[j * 2 + 0]);
        g1[j] = acc1[j] + bf2f((unsigned short)xr[j * 2 + 1]);
      }
      *(floatx4*)&gs[w][c0][r0] = g0;
      *(floatx4*)&gs[w][c0 + 16][r0] = g1;
    }
    xr = xr2;
    // same-wave in-order DS: reads below see writes above

    // LSTM update: one (row,unit) per lane
    float gi = gs[w][uu * 4 + 0][urow];
    float gf = gs[w][uu * 4 + 1][urow];
    float gg = gs[w][uu * 4 + 2][urow];
    float go = gs[w][uu * 4 + 3][urow];
    float si = 1.f / (1.f + __expf(-gi));
    float sf = 1.f / (1.f + __expf(-gf));
    float tg = tanhf(gg);
    float so = 1.f / (1.f + __expf(-go));
    c = sf * c + si * tg;
    float h = so * tanhf(c);
    if (tglob < sl) feat += h;

    // paired-lane packed h store, relaxed agent 4B
    {
      unsigned hb = (unsigned)f2bf(h);
      unsigned partner = (unsigned)__shfl_xor((int)hb, 1);
      if ((lane & 1) == 0) {
        unsigned packed = hb | (partner << 16);
        unsigned* dst = hbuf + (size_t)((tglob + 1) & 1) * HBUF_DW +
                        ((row_g * NHID + u_g) >> 1);
        __hip_atomic_store(dst, packed, __ATOMIC_RELAXED, __HIP_MEMORY_SCOPE_AGENT);
      }
    }
    if (tglob == NTIME - 1) out[128 + row_g * NHID + u_g] = h;

    // per-wave drain + flag + poll (no block barrier)
    asm volatile("s_waitcnt vmcnt(0)" ::: "memory");
    unsigned target = (unsigned)(tglob + 1);
    if (lane == 0)
      __hip_atomic_store(flags + rg * 128 + cb * 4 + w, target, __ATOMIC_RELAXED,
                         __HIP_MEMORY_SCOPE_AGENT);
    {
      const unsigned* fb = flags + rg * 128;
      unsigned v0 = __hip_atomic_load(fb + lane, __ATOMIC_RELAXED, __HIP_MEMORY_SCOPE_AGENT);
      unsigned v1 = __hip_atomic_load(fb + 64 + lane, __ATOMIC_RELAXED, __HIP_MEMORY_SCOPE_AGENT);
      while (__any((v0 < target) || (v1 < target))) {
        v0 = __hip_atomic_load(fb + lane, __ATOMIC_RELAXED, __HIP_MEMORY_SCOPE_AGENT);
        v1 = __hip_atomic_load(fb + 64 + lane, __ATOMIC_RELAXED, __HIP_MEMORY_SCOPE_AGENT);
      }
    }
  }

  cbuf[row_g * NHID + u_g] = c;
  featbuf[row_g * NHID + u_g] = feat;
  if (t0 + Tc == NTIME) out[128 + NBATCH * NHID + row_g * NHID + u_g] = c;
}

// ---------------- final FCs + log_softmax ----------------

__global__ void k_fc(const float* __restrict__ feat, const int* __restrict__ seq_len,
                     const float* __restrict__ w1, const float* __restrict__ b1,
                     const float* __restrict__ w2, const float* __restrict__ b2,
                     float* __restrict__ out) {
  int b = blockIdx.x;
  int tid = threadIdx.x;
  __shared__ float fs[NHID];
  __shared__ float x1s[H3 + 3];
  float inv = 1.f / (float)seq_len[b];
  for (int i = tid; i < NHID; i += 256) fs[i] = feat[(size_t)b * NHID + i] * inv;
  __syncthreads();
  for (int j = tid; j < H3; j += 256) {
    const float* wr = w1 + (size_t)j * NHID;
    float s = b1[j];
    for (int k = 0; k < NHID; k += 4)
      s += fs[k] * wr[k] + fs[k + 1] * wr[k + 1] + fs[k + 2] * wr[k + 2] + fs[k + 3] * wr[k + 3];
    x1s[j] = s;
  }
  __syncthreads();
  if (tid == 0) {
    float l0 = b2[0], l1 = b2[1];
    for (int k = 0; k < H3; ++k) {
      l0 += w2[k] * x1s[k];
      l1 += w2[H3 + k] * x1s[k];
    }
    float m = fmaxf(l0, l1);
    float lse = m + logf(__expf(l0 - m) + __expf(l1 - m));
    out[b * 2 + 0] = l0 - lse;
    out[b * 2 + 1] = l1 - lse;
  }
}

// ---------------- host ----------------

extern "C" void kernel_launch(void* const* d_in, const int* in_sizes, int n_in, void* d_out,
                              int out_size, void* d_ws, size_t ws_size, hipStream_t stream) {
  const int* input = (const int*)d_in[0];
  const float* hx = (const float*)d_in[1];
  const float* cx = (const float*)d_in[2];
  const int* seq_len = (const int*)d_in[3];
  const float* emb = (const float*)d_in[4];
  const float* W_ih = (const float*)d_in[5];
  const float* W_hh = (const float*)d_in[6];
  const float* b_ih = (const float*)d_in[7];
  const float* b_hh = (const float*)d_in[8];
  const float* fc1W = (const float*)d_in[9];
  const float* fc1b = (const float*)d_in[10];
  const float* fc2W = (const float*)d_in[11];
  const float* fc2b = (const float*)d_in[12];
  float* out = (float*)d_out;

  char* ws = (char*)d_ws;
  size_t off = 0;
  auto take = [&](size_t n) {
    char* p = ws + off;
    off = (off + n + 255) & ~(size_t)255;
    return p;
  };
  unsigned short* WihP = (unsigned short*)take((size_t)NGATE * NINP * 2);
  unsigned short* WhhP = (unsigned short*)take((size_t)NGATE * NHID * 2);
  float* biasP = (float*)take(NGATE * 4);
  unsigned* hbuf = (unsigned*)take((size_t)2 * HBUF_DW * 4);
  float* cbuf = (float*)take((size_t)NBATCH * NHID * 4);
  float* featbuf = (float*)take((size_t)NBATCH * NHID * 4);
  unsigned* flags = (unsigned*)take(8 * 128 * 4);  // 4KB: per-wave flags, packed
  size_t fixed = off;

  int Tc = 512;
  while (Tc > 8) {
    size_t need = fixed + ((size_t)Tc * 64 * NINP * 2 + 256) + ((size_t)Tc * 64 * NGATE * 2 + 256);
    if (need <= ws_size) break;
    Tc >>= 1;
  }
  unsigned short* Ag = (unsigned short*)take((size_t)Tc * 64 * NINP * 2);
  unsigned short* xprojF = (unsigned short*)take((size_t)Tc * 64 * NGATE * 2);

  k_pack_w<<<NGATE, 256, 0, stream>>>(W_ih, WihP, NINP);
  k_pack_w<<<NGATE, 256, 0, stream>>>(W_hh, WhhP, NHID);
  k_bias<<<NGATE / 256, 256, 0, stream>>>(b_ih, b_hh, biasP);
  k_hbuf<<<NBATCH * NHID / 256, 256, 0, stream>>>(hx, (unsigned short*)hbuf);
  hipMemsetAsync(flags, 0, 8 * 128 * 4, stream);

  for (int t0 = 0; t0 < NTIME; t0 += Tc) {
    k_gather<<<256, 256, 0, stream>>>(input, emb, Ag, t0, Tc);
    k_gemm<<<dim3(Tc * 64 / 128, NGATE / 128), 256, 0, stream>>>(Ag, WihP, biasP, xprojF, Tc * 64);
    k_rec<<<256, 256, 0, stream>>>(WhhP, xprojF, hbuf, cbuf, featbuf, cx, seq_len, out, flags, t0, Tc);
  }
  k_fc<<<NBATCH, 256, 0, stream>>>(featbuf, seq_len, fc1W, fc1b, fc2W, fc2b, out);
}

// Round 11
// 1957.409 us; speedup vs baseline: 2.9999x; 2.9999x over previous
//
#include <hip/hip_runtime.h>
#include <stdint.h>

#define NTOK  32000
#define NINP  512
#define NHID  1024
#define NBATCH 64
#define NTIME 512
#define NGATE 4096
#define H3    341   // NHID/3

typedef __attribute__((ext_vector_type(8))) short  short8;
typedef __attribute__((ext_vector_type(4))) float  floatx4;
typedef unsigned long long ull;

#define HBUF_DW (NBATCH * NHID / 2)  // 32768 dwords per h buffer

__device__ __forceinline__ unsigned short f2bf(float f) {
  union { float f; unsigned u; } v; v.f = f;
  unsigned r = v.u + 0x7fffu + ((v.u >> 16) & 1u);
  return (unsigned short)(r >> 16);
}
__device__ __forceinline__ float bf2f(unsigned short h) {
  union { unsigned u; float f; } v; v.u = ((unsigned)h) << 16;
  return v.f;
}

// packed col p -> original gate row g = q*NHID + u
// p = cb*128 + w*32 + uu*4 + q ; u = cb*32 + w*8 + uu
__device__ __forceinline__ int pack2gate(int p) {
  int cb = p >> 7, r7 = p & 127;
  int w = r7 >> 5, r5 = r7 & 31;
  int uu = r5 >> 2, q = r5 & 3;
  int u = cb * 32 + w * 8 + uu;
  return q * NHID + u;
}

// ---------------- prep kernels ----------------

__global__ void k_pack_w(const float* __restrict__ src, unsigned short* __restrict__ dst, int K) {
  int p = blockIdx.x;
  int g = pack2gate(p);
  const float* s = src + (size_t)g * K;
  unsigned short* d = dst + (size_t)p * K;
  for (int k = threadIdx.x * 2; k < K; k += 512) {
    d[k] = f2bf(s[k]);
    d[k + 1] = f2bf(s[k + 1]);
  }
}

__global__ void k_bias(const float* __restrict__ bih, const float* __restrict__ bhh,
                       float* __restrict__ bp) {
  int p = blockIdx.x * 256 + threadIdx.x;
  if (p < NGATE) { int g = pack2gate(p); bp[p] = bih[g] + bhh[g]; }
}

__global__ void k_hbuf(const float* __restrict__ hx, unsigned short* __restrict__ hbuf) {
  int i = blockIdx.x * 256 + threadIdx.x;
  if (i < NBATCH * NHID) hbuf[i] = f2bf(hx[i]);
}

// gather embeddings for one chunk: Ag[row][k] bf16, row = tl*64 + b
__global__ void k_gather(const int* __restrict__ input, const float* __restrict__ emb,
                         unsigned short* __restrict__ Ag, int t0, int Tc) {
  int total = Tc * 64 * (NINP / 8);
  for (int ci = blockIdx.x * 256 + threadIdx.x; ci < total; ci += gridDim.x * 256) {
    int row = ci >> 6;
    int k8 = (ci & 63) * 8;
    int b = row & 63;
    int tl = row >> 6;
    int tok = input[(size_t)b * NTIME + t0 + tl];
    const float* s = emb + (size_t)tok * NINP + k8;
    unsigned short* d = Ag + (size_t)row * NINP + k8;
#pragma unroll
    for (int j = 0; j < 8; ++j) d[j] = f2bf(s[j]);
  }
}

// ---------------- x_proj GEMM: [M,512] x [4096,512]^T -> bf16 [M,4096] (+bias) ----------------

__global__ __launch_bounds__(256) void k_gemm(const unsigned short* __restrict__ Ag,
                                              const unsigned short* __restrict__ Wp,
                                              const float* __restrict__ biasP,
                                              unsigned short* __restrict__ xproj, int M) {
  __shared__ __attribute__((aligned(16))) unsigned short As[128 * 64];
  __shared__ __attribute__((aligned(16))) unsigned short Bs[128 * 64];
  const int tid = threadIdx.x;
  const int lane = tid & 63;
  const int w = tid >> 6;
  const int wr = w >> 1, wc = w & 1;
  const size_t rowbase = (size_t)blockIdx.x * 128;
  const int pbase = blockIdx.y * 128;

  floatx4 z = {0.f, 0.f, 0.f, 0.f};
  floatx4 acc[4][4];
#pragma unroll
  for (int i = 0; i < 4; ++i)
#pragma unroll
    for (int j = 0; j < 4; ++j) acc[i][j] = z;

  for (int kk = 0; kk < NINP; kk += 64) {
#pragma unroll
    for (int j = 0; j < 4; ++j) {
      int ci = j * 256 + tid;
      int r = ci >> 3;
      int kb = (ci & 7) * 16;
      int dst = r * 128 + (kb ^ ((r & 7) << 4));
      *(short8*)((char*)As + dst) =
          *(const short8*)((const char*)Ag + ((rowbase + r) * NINP + kk) * 2 + kb);
      *(short8*)((char*)Bs + dst) =
          *(const short8*)((const char*)Wp + ((size_t)(pbase + r) * NINP + kk) * 2 + kb);
    }
    __syncthreads();
#pragma unroll
    for (int k32 = 0; k32 < 2; ++k32) {
      short8 af[4], bfr[4];
      int kq = k32 * 64 + (lane >> 4) * 16;
#pragma unroll
      for (int t = 0; t < 4; ++t) {
        int r = wr * 64 + t * 16 + (lane & 15);
        af[t] = *(const short8*)((const char*)As + r * 128 + (kq ^ ((r & 7) << 4)));
        int cc = wc * 64 + t * 16 + (lane & 15);
        bfr[t] = *(const short8*)((const char*)Bs + cc * 128 + (kq ^ ((cc & 7) << 4)));
      }
#pragma unroll
      for (int tm = 0; tm < 4; ++tm)
#pragma unroll
        for (int tn = 0; tn < 4; ++tn)
          acc[tm][tn] = __builtin_amdgcn_mfma_f32_16x16x32_bf16(af[tm], bfr[tn], acc[tm][tn], 0, 0, 0);
    }
    __syncthreads();
  }
#pragma unroll
  for (int tn = 0; tn < 4; ++tn) {
    int p = pbase + wc * 64 + tn * 16 + (lane & 15);
    float bv = biasP[p];
#pragma unroll
    for (int tm = 0; tm < 4; ++tm) {
      size_t r0 = rowbase + wr * 64 + tm * 16 + ((lane >> 4) * 4);
#pragma unroll
      for (int j = 0; j < 4; ++j)
        xproj[(r0 + j) * NGATE + p] = f2bf(acc[tm][tn][j] + bv);
    }
  }
}

// ---------------- persistent LSTM recurrence ----------------
// R9 structure + ONE change: h staging split by column halves so the second
// half's L3 latency hides under the first 16 MFMA ops. xproj prefetch issued
// before the h loads so its latency hides under theirs (in-order vmcnt).
// Sync protocol identical to R9: drain -> syncthreads -> 1 block flag into the
// rowgroup's single 128B line -> all-wave coalesced poll.

__global__ __launch_bounds__(256, 1) void k_rec(const unsigned short* __restrict__ Whp,
                                                const unsigned short* __restrict__ xproj,
                                                unsigned* __restrict__ hbuf,
                                                float* __restrict__ cbuf,
                                                float* __restrict__ featbuf,
                                                const float* __restrict__ cx_in,
                                                const int* __restrict__ seq_len,
                                                float* __restrict__ out,
                                                unsigned* __restrict__ flags, int t0, int Tc) {
  __shared__ __attribute__((aligned(16))) unsigned short hs[16 * NHID];  // 32KB swizzled
  __shared__ __attribute__((aligned(16))) unsigned short xs[8 * 128];    // 2KB
  __shared__ __attribute__((aligned(16))) float gs[4][32][8];            // 4KB

  const int tid = threadIdx.x;
  const int lane = tid & 63;
  const int w = tid >> 6;
  const int rg = blockIdx.x & 7;
  const int cb = blockIdx.x >> 3;
  const int colbase = cb * 128 + w * 32;

  // zero the pad rows 8..15 of hs once (never rewritten)
  {
    short8 zz = {0, 0, 0, 0, 0, 0, 0, 0};
    short8* zp = (short8*)(hs + 8 * NHID);
    for (int i = tid; i < 1024; i += 256) zp[i] = zz;
  }

  // persistent weight fragments: wave covers 32 packed cols, full K=1024
  short8 wf[64];
  {
    const int c0 = lane & 15;
    const int ke = (lane >> 4) * 8;
#pragma unroll
    for (int i = 0; i < 64; ++i) {
      int kk = i >> 1, n = i & 1;
      wf[i] = *(const short8*)(Whp + (size_t)(colbase + n * 16 + c0) * NHID + kk * 32 + ke);
    }
  }

  const int urow = lane >> 3;  // 0..7
  const int uu = lane & 7;     // 0..7
  const int row_g = rg * 8 + urow;
  const int u_g = cb * 32 + w * 8 + uu;
  float c = (t0 == 0) ? cx_in[row_g * NHID + u_g] : cbuf[row_g * NHID + u_g];
  float feat = (t0 == 0) ? 0.f : featbuf[row_g * NHID + u_g];
  const int sl = seq_len[row_g];
  const bool self = ((lane & 31) == cb);  // own-block flag slot: skip polling it

  // prefetch xproj slice for tl=0 into regs (stager: tid<128)
  short8 xreg;
  if (tid < 128) {
    int r = tid >> 4;
    int kb = (tid & 15) * 16;
    xreg = *(const short8*)((const char*)xproj +
                            ((size_t)(rg * 8 + r) * NGATE + cb * 128) * 2 + kb);
  }

  for (int tl = 0; tl < Tc; ++tl) {
    const int tglob = t0 + tl;
    // dword-unit arithmetic on unsigned* base, THEN cast (R5 lesson)
    const short8* hp =
        (const short8*)(hbuf + (size_t)(tglob & 1) * HBUF_DW + (size_t)rg * 8 * (NHID / 2));

    // write current step's x slice (prefetched last iter) into LDS
    if (tid < 128) {
      int r = tid >> 4;
      int kb = (tid & 15) * 16;
      *(short8*)((char*)xs + r * 256 + kb) = xreg;
    }

    // issue next step's x prefetch BEFORE the h loads: its latency hides
    // under theirs (vmcnt completes in issue order, so the waits below stay exact)
    if (tid < 128 && tl + 1 < Tc) {
      int r = tid >> 4;
      int kb = (tid & 15) * 16;
      xreg = *(const short8*)((const char*)xproj +
                              ((size_t)((tl + 1) * 64 + rg * 8 + r) * NGATE + cb * 128) * 2 + kb);
    }

    // stage h split by column halves:
    //   q0,q1 = rows 0-3 / 4-7, cols 0..511 ; q2,q3 = same rows, cols 512..1023
    const int r01 = tid >> 6;   // 0..3
    const int r45 = 4 + r01;
    const int cw = tid & 63;    // 16B-word within half-row
    const short8* a0p = hp + r01 * 128 + cw;
    const short8* a1p = hp + r45 * 128 + cw;
    short8 q0, q1, q2, q3;
    asm volatile(
        "global_load_dwordx4 %0, %4, off sc1\n\t"
        "global_load_dwordx4 %1, %5, off sc1\n\t"
        "global_load_dwordx4 %2, %6, off sc1\n\t"
        "global_load_dwordx4 %3, %7, off sc1\n\t"
        "s_waitcnt vmcnt(2)"   // q0,q1 (and xreg prefetch) complete; q2,q3 in flight
        : "=&v"(q0), "=&v"(q1), "=&v"(q2), "=&v"(q3)
        : "v"(a0p), "v"(a1p), "v"(a0p + 64), "v"(a1p + 64)
        : "memory");
    {
      int kb = cw * 16;
      *(short8*)((char*)hs + r01 * 2048 + (kb ^ ((r01 & 7) << 4))) = q0;
      *(short8*)((char*)hs + r45 * 2048 + (kb ^ ((r45 & 7) << 4))) = q1;
    }
    __syncthreads();  // A1: cols 0..511 staged (+ xs visible)

    // gates = h @ Whp^T, fp32 accum, 4-acc interleave — FIRST HALF (kk 0..15)
    floatx4 acc0a = {0.f, 0.f, 0.f, 0.f}, acc0b = {0.f, 0.f, 0.f, 0.f};
    floatx4 acc1a = {0.f, 0.f, 0.f, 0.f}, acc1b = {0.f, 0.f, 0.f, 0.f};
    const int rr = lane & 15;
    const int kq = (lane >> 4) * 16;
#pragma unroll
    for (int kk = 0; kk < 16; kk += 2) {
      int kb0 = kk * 64 + kq;
      int kb1 = (kk + 1) * 64 + kq;
      short8 a0 = *(const short8*)((const char*)hs + rr * 2048 + (kb0 ^ ((rr & 7) << 4)));
      short8 a1 = *(const short8*)((const char*)hs + rr * 2048 + (kb1 ^ ((rr & 7) << 4)));
      acc0a = __builtin_amdgcn_mfma_f32_16x16x32_bf16(a0, wf[2 * kk + 0], acc0a, 0, 0, 0);
      acc1a = __builtin_amdgcn_mfma_f32_16x16x32_bf16(a0, wf[2 * kk + 1], acc1a, 0, 0, 0);
      acc0b = __builtin_amdgcn_mfma_f32_16x16x32_bf16(a1, wf[2 * kk + 2], acc0b, 0, 0, 0);
      acc1b = __builtin_amdgcn_mfma_f32_16x16x32_bf16(a1, wf[2 * kk + 3], acc1b, 0, 0, 0);
    }

    // mid-point: q2,q3 have had the whole first half to land
    asm volatile("s_waitcnt vmcnt(0)" : "+v"(q2), "+v"(q3) :: "memory");
    {
      int kb = 1024 + cw * 16;
      *(short8*)((char*)hs + r01 * 2048 + (kb ^ ((r01 & 7) << 4))) = q2;
      *(short8*)((char*)hs + r45 * 2048 + (kb ^ ((r45 & 7) << 4))) = q3;
    }
    __syncthreads();  // A2: cols 512..1023 staged

    // SECOND HALF (kk 16..31)
#pragma unroll
    for (int kk = 16; kk < 32; kk += 2) {
      int kb0 = kk * 64 + kq;
      int kb1 = (kk + 1) * 64 + kq;
      short8 a0 = *(const short8*)((const char*)hs + rr * 2048 + (kb0 ^ ((rr & 7) << 4)));
      short8 a1 = *(const short8*)((const char*)hs + rr * 2048 + (kb1 ^ ((rr & 7) << 4)));
      acc0a = __builtin_amdgcn_mfma_f32_16x16x32_bf16(a0, wf[2 * kk + 0], acc0a, 0, 0, 0);
      acc1a = __builtin_amdgcn_mfma_f32_16x16x32_bf16(a0, wf[2 * kk + 1], acc1a, 0, 0, 0);
      acc0b = __builtin_amdgcn_mfma_f32_16x16x32_bf16(a1, wf[2 * kk + 2], acc0b, 0, 0, 0);
      acc1b = __builtin_amdgcn_mfma_f32_16x16x32_bf16(a1, wf[2 * kk + 3], acc1b, 0, 0, 0);
    }
    floatx4 acc0 = acc0a + acc0b;
    floatx4 acc1 = acc1a + acc1b;

    // add x_proj, dump gates to per-wave LDS (valid lanes: rows 0..7)
    if (lane < 32) {
      int r0 = (lane >> 4) * 4;
      int c0 = lane & 15;
      floatx4 g0, g1;
#pragma unroll
      for (int j = 0; j < 4; ++j) {
        g0[j] = acc0[j] + bf2f(xs[(r0 + j) * 128 + w * 32 + c0]);
        g1[j] = acc1[j] + bf2f(xs[(r0 + j) * 128 + w * 32 + c0 + 16]);
      }
      *(floatx4*)&gs[w][c0][r0] = g0;
      *(floatx4*)&gs[w][c0 + 16][r0] = g1;
    }
    // same-wave in-order DS: reads below see writes above

    // LSTM update: one (row,unit) per lane
    float gi = gs[w][uu * 4 + 0][urow];
    float gf = gs[w][uu * 4 + 1][urow];
    float gg = gs[w][uu * 4 + 2][urow];
    float go = gs[w][uu * 4 + 3][urow];
    float si = 1.f / (1.f + __expf(-gi));
    float sf = 1.f / (1.f + __expf(-gf));
    float tg = tanhf(gg);
    float so = 1.f / (1.f + __expf(-go));
    c = sf * c + si * tg;
    float h = so * tanhf(c);
    if (tglob < sl) feat += h;

    // paired-lane packed h store, relaxed agent 4B (fire-and-forget)
    {
      unsigned hb = (unsigned)f2bf(h);
      unsigned partner = (unsigned)__shfl_xor((int)hb, 1);
      if ((lane & 1) == 0) {
        unsigned packed = hb | (partner << 16);
        unsigned* dst = hbuf + (size_t)((tglob + 1) & 1) * HBUF_DW +
                        ((row_g * NHID + u_g) >> 1);
        __hip_atomic_store(dst, packed, __ATOMIC_RELAXED, __HIP_MEMORY_SCOPE_AGENT);
      }
    }
    if (tglob == NTIME - 1) out[128 + row_g * NHID + u_g] = h;

    // barrier: drain own stores, block flag into rowgroup's single 128B line
    asm volatile("s_waitcnt vmcnt(0)" ::: "memory");
    __syncthreads();  // (B) all waves' h stores drained; all xs/hs reads done
    unsigned target = (unsigned)(tglob + 1);
    if (tid == 0)
      __hip_atomic_store(flags + rg * 32 + cb, target, __ATOMIC_RELAXED,
                         __HIP_MEMORY_SCOPE_AGENT);
    // all-wave busy poll: 64 lanes cover the 32-flag line twice (coalesced)
    {
      const unsigned* slot = flags + rg * 32 + (lane & 31);
      unsigned v = self ? 0xFFFFFFFFu
                        : __hip_atomic_load(slot, __ATOMIC_RELAXED, __HIP_MEMORY_SCOPE_AGENT);
      while (__any(v < target)) {
        v = self ? 0xFFFFFFFFu
                 : __hip_atomic_load(slot, __ATOMIC_RELAXED, __HIP_MEMORY_SCOPE_AGENT);
      }
    }
    // no trailing syncthreads needed: A1 of next iter orders hs/xs rewrites
  }

  cbuf[row_g * NHID + u_g] = c;
  featbuf[row_g * NHID + u_g] = feat;
  if (t0 + Tc == NTIME) out[128 + NBATCH * NHID + row_g * NHID + u_g] = c;
}

// ---------------- final FCs + log_softmax ----------------

__global__ void k_fc(const float* __restrict__ feat, const int* __restrict__ seq_len,
                     const float* __restrict__ w1, const float* __restrict__ b1,
                     const float* __restrict__ w2, const float* __restrict__ b2,
                     float* __restrict__ out) {
  int b = blockIdx.x;
  int tid = threadIdx.x;
  __shared__ float fs[NHID];
  __shared__ float x1s[H3 + 3];
  float inv = 1.f / (float)seq_len[b];
  for (int i = tid; i < NHID; i += 256) fs[i] = feat[(size_t)b * NHID + i] * inv;
  __syncthreads();
  for (int j = tid; j < H3; j += 256) {
    const float* wr = w1 + (size_t)j * NHID;
    float s = b1[j];
    for (int k = 0; k < NHID; k += 4)
      s += fs[k] * wr[k] + fs[k + 1] * wr[k + 1] + fs[k + 2] * wr[k + 2] + fs[k + 3] * wr[k + 3];
    x1s[j] = s;
  }
  __syncthreads();
  if (tid == 0) {
    float l0 = b2[0], l1 = b2[1];
    for (int k = 0; k < H3; ++k) {
      l0 += w2[k] * x1s[k];
      l1 += w2[H3 + k] * x1s[k];
    }
    float m = fmaxf(l0, l1);
    float lse = m + logf(__expf(l0 - m) + __expf(l1 - m));
    out[b * 2 + 0] = l0 - lse;
    out[b * 2 + 1] = l1 - lse;
  }
}

// ---------------- host ----------------

extern "C" void kernel_launch(void* const* d_in, const int* in_sizes, int n_in, void* d_out,
                              int out_size, void* d_ws, size_t ws_size, hipStream_t stream) {
  const int* input = (const int*)d_in[0];
  const float* hx = (const float*)d_in[1];
  const float* cx = (const float*)d_in[2];
  const int* seq_len = (const int*)d_in[3];
  const float* emb = (const float*)d_in[4];
  const float* W_ih = (const float*)d_in[5];
  const float* W_hh = (const float*)d_in[6];
  const float* b_ih = (const float*)d_in[7];
  const float* b_hh = (const float*)d_in[8];
  const float* fc1W = (const float*)d_in[9];
  const float* fc1b = (const float*)d_in[10];
  const float* fc2W = (const float*)d_in[11];
  const float* fc2b = (const float*)d_in[12];
  float* out = (float*)d_out;

  char* ws = (char*)d_ws;
  size_t off = 0;
  auto take = [&](size_t n) {
    char* p = ws + off;
    off = (off + n + 255) & ~(size_t)255;
    return p;
  };
  unsigned short* WihP = (unsigned short*)take((size_t)NGATE * NINP * 2);
  unsigned short* WhhP = (unsigned short*)take((size_t)NGATE * NHID * 2);
  float* biasP = (float*)take(NGATE * 4);
  unsigned* hbuf = (unsigned*)take((size_t)2 * HBUF_DW * 4);
  float* cbuf = (float*)take((size_t)NBATCH * NHID * 4);
  float* featbuf = (float*)take((size_t)NBATCH * NHID * 4);
  unsigned* flags = (unsigned*)take(8 * 32 * 4);  // 1KB: one 128B line per rowgroup
  size_t fixed = off;

  int Tc = 512;
  while (Tc > 8) {
    size_t need = fixed + ((size_t)Tc * 64 * NINP * 2 + 256) + ((size_t)Tc * 64 * NGATE * 2 + 256);
    if (need <= ws_size) break;
    Tc >>= 1;
  }
  unsigned short* Ag = (unsigned short*)take((size_t)Tc * 64 * NINP * 2);
  unsigned short* xproj = (unsigned short*)take((size_t)Tc * 64 * NGATE * 2);

  k_pack_w<<<NGATE, 256, 0, stream>>>(W_ih, WihP, NINP);
  k_pack_w<<<NGATE, 256, 0, stream>>>(W_hh, WhhP, NHID);
  k_bias<<<NGATE / 256, 256, 0, stream>>>(b_ih, b_hh, biasP);
  k_hbuf<<<NBATCH * NHID / 256, 256, 0, stream>>>(hx, (unsigned short*)hbuf);
  hipMemsetAsync(flags, 0, 8 * 32 * 4, stream);

  for (int t0 = 0; t0 < NTIME; t0 += Tc) {
    k_gather<<<256, 256, 0, stream>>>(input, emb, Ag, t0, Tc);
    k_gemm<<<dim3(Tc * 64 / 128, NGATE / 128), 256, 0, stream>>>(Ag, WihP, biasP, xproj, Tc * 64);
    k_rec<<<256, 256, 0, stream>>>(WhhP, xproj, hbuf, cbuf, featbuf, cx, seq_len, out, flags, t0, Tc);
  }
  k_fc<<<NBATCH, 256, 0, stream>>>(featbuf, seq_len, fc1W, fc1b, fc2W, fc2b, out);
}